// Round 12
// baseline (668.636 us; speedup 1.0000x reference)
//
#include <hip/hip_runtime.h>
#include <hip/hip_bf16.h>
#include <math.h>

#define F_IN 256
#define F_OUT 64
#define NEG_SLOPE 0.2f

__device__ __forceinline__ float bf2f(__hip_bfloat16 v) {
    return __bfloat162float(v);
}

typedef short short8 __attribute__((ext_vector_type(8)));
typedef float f32x4 __attribute__((ext_vector_type(4)));

// RNE float->bf16 bits (finite inputs)
__device__ __forceinline__ unsigned int bf16_bits(float v) {
    unsigned int u = __float_as_uint(v);
    return (u + 0x7fffu + ((u >> 16) & 1u)) >> 16;
}

// ---------------------------------------------------------------------------
// MFMA GEMM: h16 = bf16(x @ W) [PERMUTED layout], a_src = h@att_src,
// a_dst = h@att_dst.  bf16x3 split (xh*Wh + xl*Wh + xh*Wl) ~ fp32 accuracy.
//
// v4 (verified R4): depth-2 software pipeline in q (only cur/nxt float4 pairs
// live, sched_barrier(0) pins it) -> no scratch spill. (512,2): 16 waves/CU,
// VGPR 128, LDS 64 KB. h16 stored PERMUTED (phys fr*4+c = logical c*16+fr):
// 8-B/lane stores, 4 full 128-B rows per instruction.
// ---------------------------------------------------------------------------
#define WHI(q, c, l) (((((q)*4 + (c)) * 64) + (l)) * 8)
#define WLO(q, c, l) (16384 + WHI(q, c, l))

__global__ __launch_bounds__(512, 2) void gemm_kernel(
    const float* __restrict__ x, const float* __restrict__ W,
    const float* __restrict__ att_src, const float* __restrict__ att_dst,
    __hip_bfloat16* __restrict__ h16, float* __restrict__ a_src,
    float* __restrict__ a_dst, int N, int nTiles)
{
    __shared__ unsigned short sW[32768];   // [hi|lo][q][c][lane][e] = 64 KB

    const int t = threadIdx.x;
    const int lane = t & 63;
    const int w = t >> 6;          // wave id (0..7)
    const int g = lane >> 4;       // k-block group (0..3)
    const int fr = lane & 15;      // A-row / B-col / D-col within fragment

    // ---- stage W as hi/lo bf16 fragments (once per block) ----
    for (int idx = t; idx < 2048; idx += 512) {
        const int q = idx >> 8;
        const int c = (idx >> 6) & 3;
        const int l = idx & 63;
        const int col = c * 16 + (l & 15);
        const float* wp = W + (size_t)(q * 32 + ((l >> 4) * 8)) * F_OUT + col;
        short8 hv, lv;
#pragma unroll
        for (int e = 0; e < 8; e++) {
            float wv = wp[(size_t)e * F_OUT];
            unsigned int hb = bf16_bits(wv);
            float hf = __uint_as_float(hb << 16);
            unsigned int lb = bf16_bits(wv - hf);
            hv[e] = (short)hb;
            lv[e] = (short)lb;
        }
        *(short8*)&sW[WHI(q, c, l)] = hv;
        *(short8*)&sW[WLO(q, c, l)] = lv;
    }
    __syncthreads();

    // per-lane attention weight slices (4 cols each, cached)
    float as4[4], ad4[4];
#pragma unroll
    for (int c = 0; c < 4; c++) {
        as4[c] = att_src[c * 16 + fr];
        ad4[c] = att_dst[c * 16 + fr];
    }

    const float4 z4 = make_float4(0.f, 0.f, 0.f, 0.f);

    for (int tile = blockIdx.x; tile < nTiles; tile += gridDim.x) {
        const int R0 = tile * 128 + w * 16;
        const int rowA = R0 + fr;
        const bool okA = rowA < N;
        const float* xrow = x + (size_t)rowA * F_IN + g * 8;

        f32x4 acc[4];
#pragma unroll
        for (int c = 0; c < 4; c++) acc[c] = (f32x4){0.f, 0.f, 0.f, 0.f};

        // depth-2 pipeline: only 4 float4 of x live at any time
        float4 cur0 = okA ? *(const float4*)(xrow + 0) : z4;
        float4 cur1 = okA ? *(const float4*)(xrow + 4) : z4;

#pragma unroll
        for (int q = 0; q < 8; q++) {
            float4 nxt0 = z4, nxt1 = z4;
            if (q < 7) {
                nxt0 = okA ? *(const float4*)(xrow + (q + 1) * 32)     : z4;
                nxt1 = okA ? *(const float4*)(xrow + (q + 1) * 32 + 4) : z4;
            }

            const float vf[8] = {cur0.x, cur0.y, cur0.z, cur0.w,
                                 cur1.x, cur1.y, cur1.z, cur1.w};
            short8 ahi, alo;
#pragma unroll
            for (int e = 0; e < 8; e++) {
                unsigned int hb = bf16_bits(vf[e]);
                float hf = __uint_as_float(hb << 16);
                unsigned int lb = bf16_bits(vf[e] - hf);
                ahi[e] = (short)hb;
                alo[e] = (short)lb;
            }
#pragma unroll
            for (int c = 0; c < 4; c++) {
                short8 bh = *(const short8*)&sW[WHI(q, c, lane)];
                short8 bl = *(const short8*)&sW[WLO(q, c, lane)];
                acc[c] = __builtin_amdgcn_mfma_f32_16x16x32_bf16(ahi, bh, acc[c], 0, 0, 0);
                acc[c] = __builtin_amdgcn_mfma_f32_16x16x32_bf16(alo, bh, acc[c], 0, 0, 0);
                acc[c] = __builtin_amdgcn_mfma_f32_16x16x32_bf16(ahi, bl, acc[c], 0, 0, 0);
            }
            cur0 = nxt0;
            cur1 = nxt1;
            __builtin_amdgcn_sched_barrier(0);   // pin pipeline depth (no re-hoist)
        }

        // ---- epilogue: a_src/a_dst partials ----
        float sr[4] = {0.f, 0.f, 0.f, 0.f};
        float sd[4] = {0.f, 0.f, 0.f, 0.f};
#pragma unroll
        for (int c = 0; c < 4; c++) {
#pragma unroll
            for (int r = 0; r < 4; r++) {
                float v = acc[c][r];
                sr[r] = fmaf(v, as4[c], sr[r]);
                sd[r] = fmaf(v, ad4[c], sd[r]);
            }
        }
#pragma unroll
        for (int off = 1; off <= 8; off <<= 1) {
#pragma unroll
            for (int r = 0; r < 4; r++) {
                sr[r] += __shfl_xor(sr[r], off, 64);
                sd[r] += __shfl_xor(sd[r], off, 64);
            }
        }

        // ---- h16 store: permuted layout, 8 B/lane, 4 full rows / instr ----
#pragma unroll
        for (int r = 0; r < 4; r++) {
            const int row = R0 + g * 4 + r;
            if (row < N) {
                unsigned int lo = bf16_bits(acc[0][r]) | (bf16_bits(acc[1][r]) << 16);
                unsigned int hi = bf16_bits(acc[2][r]) | (bf16_bits(acc[3][r]) << 16);
                *(int2*)(h16 + (size_t)row * F_OUT + fr * 4) = make_int2((int)lo, (int)hi);
            }
        }

        if (fr < 4) {
            const int row = R0 + g * 4 + fr;
            if (row < N) {
                float vs = (fr == 0) ? sr[0] : (fr == 1) ? sr[1] : (fr == 2) ? sr[2] : sr[3];
                float vd = (fr == 0) ? sd[0] : (fr == 1) ? sd[1] : (fr == 2) ? sd[2] : sd[3];
                a_src[row] = vs;
                a_dst[row] = vd;
            }
        }
    }
}

// ---------------------------------------------------------------------------
// Prep pipeline v2 (R9 theory; R11 resubmission after code audit — no OOB,
// no misalignment, no data-dependent loops, graph-safe, replay-idempotent).
//   zero(deg) -> deg_count (global atomics, L2-resident 400 KB) ->
//   3-phase scan (row_ptr) -> bin_direct (atomicSub slot assignment, one
//   pass, NO sort). rec[] holds raw j; order within a node is irrelevant.
// Replaces the old 5-kernel count/colscan/bbase/bin/sort machinery.
// ---------------------------------------------------------------------------
__global__ __launch_bounds__(1024) void zero_kernel(int* __restrict__ p, int n)
{
    const int i = blockIdx.x * 1024 + threadIdx.x;
    if (i < n) p[i] = 0;
}

__global__ __launch_bounds__(256) void deg_count_kernel(
    const int* __restrict__ dst, int* __restrict__ deg, int E)
{
    const int e = (blockIdx.x * 256 + threadIdx.x) * 4;
    if (e + 3 < E) {
        int4 d = *(const int4*)&dst[e];
        atomicAdd(&deg[d.x], 1);
        atomicAdd(&deg[d.y], 1);
        atomicAdd(&deg[d.z], 1);
        atomicAdd(&deg[d.w], 1);
    } else if (e < E) {
        for (int q = e; q < E; q++) atomicAdd(&deg[dst[q]], 1);
    }
}

// per-1024-chunk partial sums
__global__ __launch_bounds__(1024) void scan_part_kernel(
    const int* __restrict__ deg, int* __restrict__ psum, int N)
{
    __shared__ int s[1024];
    const int t = threadIdx.x;
    const int i = blockIdx.x * 1024 + t;
    s[t] = (i < N) ? deg[i] : 0;
    __syncthreads();
    for (int off = 512; off > 0; off >>= 1) {
        if (t < off) s[t] += s[t + off];
        __syncthreads();
    }
    if (t == 0) psum[blockIdx.x] = s[0];
}

// exclusive scan of the P chunk sums (P <= 1024); also row_ptr[N] = E
__global__ __launch_bounds__(1024) void scan_base_kernel(
    int* __restrict__ psum, int P, int* __restrict__ row_ptr, int N, int E)
{
    __shared__ int s[1024];
    const int t = threadIdx.x;
    int v = (t < P) ? psum[t] : 0;
    s[t] = v;
    __syncthreads();
    for (int off = 1; off < 1024; off <<= 1) {
        int u = (t >= off) ? s[t - off] : 0;
        __syncthreads();
        s[t] += u;
        __syncthreads();
    }
    if (t < P) psum[t] = s[t] - v;        // exclusive chunk base
    if (t == 0) row_ptr[N] = E;
}

// chunk-local exclusive scan + chunk base -> row_ptr (deg preserved)
__global__ __launch_bounds__(1024) void scan_write_kernel(
    const int* __restrict__ deg, const int* __restrict__ psum,
    int* __restrict__ row_ptr, int N)
{
    __shared__ int s[1024];
    const int t = threadIdx.x;
    const int i = blockIdx.x * 1024 + t;
    int v = (i < N) ? deg[i] : 0;
    s[t] = v;
    __syncthreads();
    for (int off = 1; off < 1024; off <<= 1) {
        int u = (t >= off) ? s[t - off] : 0;
        __syncthreads();
        s[t] += u;
        __syncthreads();
    }
    if (i < N) row_ptr[i] = psum[blockIdx.x] + s[t] - v;
}

// one-pass slot assignment: old = atomicSub(deg) -> final slot. deg ends 0.
__global__ __launch_bounds__(256) void bin_direct_kernel(
    const int* __restrict__ ei, const int* __restrict__ row_ptr,
    int* __restrict__ deg, int* __restrict__ rec, int E)
{
    const int e = (blockIdx.x * 256 + threadIdx.x) * 4;
    if (e + 3 < E) {
        int4 jj = *(const int4*)&ei[e];
        int4 ii = *(const int4*)&ei[E + e];
        int o0 = atomicSub(&deg[ii.x], 1);
        int o1 = atomicSub(&deg[ii.y], 1);
        int o2 = atomicSub(&deg[ii.z], 1);
        int o3 = atomicSub(&deg[ii.w], 1);
        rec[row_ptr[ii.x] + o0 - 1] = jj.x;
        rec[row_ptr[ii.y] + o1 - 1] = jj.y;
        rec[row_ptr[ii.z] + o2 - 1] = jj.z;
        rec[row_ptr[ii.w] + o3 - 1] = jj.w;
    } else if (e < E) {
        for (int q = e; q < E; q++) {
            int j = ei[q], i = ei[E + q];
            int o = atomicSub(&deg[i], 1);
            rec[row_ptr[i] + o - 1] = j;
        }
    }
}

// ---------------------------------------------------------------------------
// Node aggregation v4 (verified R7: 63.2 us, VGPR 32, 0 bank conflicts).
//  - Dynamic group bound G = ceil(cnt/4): unrolled 16x with wave-uniform
//    guard (d[16] statically indexed -> registers).
//  - j/p broadcast via 2 KB LDS, ds_read at immediate offsets (quarter
//    lanes share an address -> broadcast). sched_barrier(0) pins order.
//  - Wide gathers: 4 rows/instr (quarter q -> row j[4g+q], sub-lane a ->
//    int2 = phys cols 4a..4a+3), issued before p-compute waits on a_src.
// h16 PERMUTED: phys 4a+c = logical c*16+a.
// ---------------------------------------------------------------------------
__global__ __launch_bounds__(256) void node_kernel(
    const __hip_bfloat16* __restrict__ h16, const float* __restrict__ a_src,
    const float* __restrict__ a_dst, const int* __restrict__ row_ptr,
    const int* __restrict__ rec, const float* __restrict__ bias,
    float* __restrict__ out, int N)
{
    __shared__ int   sj[4][64];
    __shared__ float sp[4][64];

    const int w = threadIdx.x >> 6;
    const int lane = threadIdx.x & 63;
    const int i = blockIdx.x * 4 + w;
    if (i >= N) return;

    const int q = lane >> 4;        // row-quarter this lane serves in gathers
    const int a = lane & 15;        // int2 sub-index (phys cols 4a..4a+3)
    const unsigned short* __restrict__ hb = (const unsigned short*)h16;
    const unsigned short* __restrict__ hba = hb + a * 4;

    int*   sjw = &sj[w][0];
    float* spw = &sp[w][0];
    const int*   sjq = &sj[w][q];   // per-lane read base (offset 16g bytes/4)
    const float* spq = &sp[w][q];

    const int s = row_ptr[i];
    const int e = row_ptr[i + 1];

    const float adst_i = a_dst[i];
    float vs = a_src[i] + adst_i;
    vs = fmaxf(vs, NEG_SLOPE * vs);              // LeakyReLU(0.2)
    const float pself = __expf(vs);
    float denl = (lane == 0) ? pself : 0.f;

    float acc0 = 0.f, acc1 = 0.f, acc2 = 0.f, acc3 = 0.f;

    for (int k = s; k < e; k += 64) {
        const int cnt = min(64, e - k);          // wave-uniform
        const int G = (cnt + 3) >> 2;            // active 4-row groups
        int r = (lane < cnt) ? rec[k + lane] : 0;      // coalesced
        int j = r & 0x1FFFF;
        sjw[lane] = j;

        float asj = a_src[j];                          // scattered gather (A)
        __builtin_amdgcn_sched_barrier(0);             // j visible before reads

        // issue the G row-gathers (4 rows / instr) before waiting on A
        int2 d[16];
#pragma unroll
        for (int g = 0; g < 16; g++) {
            if (g < G) {
                int jsel = sjq[4 * g];                 // ds_read, imm offset
                d[g] = *(const int2*)(hba + (size_t)jsel * F_OUT);
            }
        }

        // p-compute (vmcnt retires a_src first; d[] stays in flight)
        float v = asj + adst_i;
        v = fmaxf(v, NEG_SLOPE * v);
        float p = __expf(v);                           // ONE exp / 64 edges
        if (lane >= cnt) p = 0.f;
        denl += p;
        spw[lane] = p;
        __builtin_amdgcn_sched_barrier(0);             // p visible before reads

        // consume: psel from LDS, unpack + 4 fma per active group
#pragma unroll
        for (int g = 0; g < 16; g++) {
            if (g < G) {
                float psel = spq[4 * g];               // ds_read, imm offset
                unsigned int lo = (unsigned int)d[g].x;
                unsigned int hi = (unsigned int)d[g].y;
                acc0 = fmaf(psel, __uint_as_float(lo << 16), acc0);
                acc1 = fmaf(psel, __uint_as_float(lo & 0xFFFF0000u), acc1);
                acc2 = fmaf(psel, __uint_as_float(hi << 16), acc2);
                acc3 = fmaf(psel, __uint_as_float(hi & 0xFFFF0000u), acc3);
            }
        }
        __builtin_amdgcn_sched_barrier(0);             // protect sj/sp reuse
    }

    // combine the 4 quarters (every lane ends with the full column sums)
#pragma unroll
    for (int o = 16; o <= 32; o <<= 1) {
        acc0 += __shfl_xor(acc0, o, 64);
        acc1 += __shfl_xor(acc1, o, 64);
        acc2 += __shfl_xor(acc2, o, 64);
        acc3 += __shfl_xor(acc3, o, 64);
    }
    float den = denl;
#pragma unroll
    for (int o = 32; o > 0; o >>= 1) den += __shfl_xor(den, o, 64);
    den += 1e-16f;

    if (lane < 16) {
        // self-loop term + bias + store (4 x 64-B coalesced dword stores)
        int2 hs = *(const int2*)(hb + (size_t)i * F_OUT + a * 4);
        unsigned int lo = (unsigned int)hs.x, hi = (unsigned int)hs.y;
        float s0 = acc0 + pself * __uint_as_float(lo << 16);
        float s1 = acc1 + pself * __uint_as_float(lo & 0xFFFF0000u);
        float s2 = acc2 + pself * __uint_as_float(hi << 16);
        float s3 = acc3 + pself * __uint_as_float(hi & 0xFFFF0000u);
        float* orow = out + (size_t)i * F_OUT;
        orow[ 0 + a] = s0 / den + bias[ 0 + a];
        orow[16 + a] = s1 / den + bias[16 + a];
        orow[32 + a] = s2 / den + bias[32 + a];
        orow[48 + a] = s3 / den + bias[48 + a];
    }
}

// ---------------------------------------------------------------------------
extern "C" void kernel_launch(void* const* d_in, const int* in_sizes, int n_in,
                              void* d_out, int out_size, void* d_ws, size_t ws_size,
                              hipStream_t stream)
{
    const float* x      = (const float*)d_in[0];
    const int*   ei     = (const int*)d_in[1];
    const float* W      = (const float*)d_in[2];
    const float* att_sr = (const float*)d_in[3];
    const float* att_ds = (const float*)d_in[4];
    const float* bias   = (const float*)d_in[5];
    float* out = (float*)d_out;

    const int N = in_sizes[0] / F_IN;
    const int E = in_sizes[1] / 2;

    char* ws = (char*)d_ws;
    size_t off = 0;
    auto alloc = [&](size_t bytes) -> void* {
        void* p = ws + off;
        off = (off + bytes + 255) & ~(size_t)255;
        return p;
    };
    __hip_bfloat16* h16 = (__hip_bfloat16*)alloc((size_t)N * F_OUT * 2);
    float* a_src   = (float*)alloc((size_t)N * 4);
    float* a_dst   = (float*)alloc((size_t)N * 4);
    int*   deg     = (int*)alloc((size_t)N * 4);
    int*   psum    = (int*)alloc((size_t)1024 * 4);
    int*   row_ptr = (int*)alloc((size_t)(N + 1) * 4);
    int*   rec     = (int*)alloc((size_t)E * 4);
    (void)ws_size; (void)n_in; (void)out_size;

    const int nTiles = (N + 127) >> 7;                      // 128-row tiles
    const int gemmGrid = nTiles < 512 ? nTiles : 512;       // 2 blocks/CU
    const int edgeGrid = (E + 1023) / 1024;                 // 4 edges/thread
    const int P = (N + 1023) >> 10;                         // scan chunks

    zero_kernel<<<P, 1024, 0, stream>>>(deg, N);
    gemm_kernel<<<gemmGrid, 512, 0, stream>>>(x, W, att_sr, att_ds, h16, a_src, a_dst, N, nTiles);
    deg_count_kernel<<<edgeGrid, 256, 0, stream>>>(ei + E, deg, E);
    scan_part_kernel<<<P, 1024, 0, stream>>>(deg, psum, N);
    scan_base_kernel<<<1, 1024, 0, stream>>>(psum, P, row_ptr, N, E);
    scan_write_kernel<<<P, 1024, 0, stream>>>(deg, psum, row_ptr, N);
    bin_direct_kernel<<<edgeGrid, 256, 0, stream>>>(ei, row_ptr, deg, rec, E);
    node_kernel<<<(N + 3) / 4, 256, 0, stream>>>(h16, a_src, a_dst, row_ptr, rec, bias, out, N);
}